// Round 15
// baseline (238.674 us; speedup 1.0000x reference)
//
#include <hip/hip_runtime.h>
#include <hip/hip_bf16.h>
#include <stdint.h>

typedef unsigned short u16;
typedef __bf16 bf16x8 __attribute__((ext_vector_type(8)));
typedef float f32x4 __attribute__((ext_vector_type(4)));

#define MTOT 65536

__device__ __forceinline__ u16 f2b(float f) {
    uint32_t u = __float_as_uint(f);
    u += 0x7fffu + ((u >> 16) & 1u);
    return (u16)(u >> 16);
}
__device__ __forceinline__ float b2f(u16 h) {
    return __uint_as_float(((uint32_t)h) << 16);
}

__device__ __forceinline__ uint32_t pk2(float a, float b) {
    uint32_t r;
    asm("v_cvt_pk_bf16_f32 %0, %1, %2" : "=v"(r) : "v"(a), "v"(b));
    return r;
}

// LDS 16B-chunk swizzle: chunk c of row r lives at slot c ^ swz8(r).
__device__ __forceinline__ int swz8(int r) { return (r ^ (r >> 3)) & 7; }

__device__ __forceinline__ void gload16(const void* g, void* l) {
    __builtin_amdgcn_global_load_lds((const __attribute__((address_space(1))) void*)g,
                                     (__attribute__((address_space(3))) void*)l, 16, 0, 0);
}

// stage a [32*NWAVES x 64] bf16 tile via global_load_lds (4 ops/thread).
__device__ __forceinline__ void stage_tile(const char* gbase, size_t ldb,
                                           u16* lbuf, int wave, int lane) {
    int lr = lane >> 3, lc = lane & 7;
#pragma unroll
    for (int i = 0; i < 4; ++i) {
        int r = wave * 32 + i * 8 + lr;
        int csrc = lc ^ swz8(r);
        gload16(gbase + (size_t)r * ldb + csrc * 16, lbuf + (wave * 32 + i * 8) * 64);
    }
}

// explicit fragment ds_reads for one 32-wide k-slab
__device__ __forceinline__ void loadfrags(const u16* As, const u16* Ws, int kk,
                                          int wm, int wn, int l16, int q,
                                          bf16x8 (&af)[4], bf16x8 (&wf)[4]) {
    int c0 = kk * 4 + q;
#pragma unroll
    for (int mi = 0; mi < 4; ++mi) {
        int r = wm * 64 + mi * 16 + l16;
        af[mi] = *(const bf16x8*)&As[r * 64 + ((c0 ^ swz8(r)) << 3)];
    }
#pragma unroll
    for (int ni = 0; ni < 4; ++ni) {
        int r = wn * 64 + ni * 16 + l16;
        wf[ni] = *(const bf16x8*)&Ws[r * 64 + ((c0 ^ swz8(r)) << 3)];
    }
}
__device__ __forceinline__ void mfma16(const bf16x8 (&af)[4], const bf16x8 (&wf)[4],
                                       f32x4 (&acc)[4][4]) {
#pragma unroll
    for (int mi = 0; mi < 4; ++mi)
#pragma unroll
        for (int ni = 0; ni < 4; ++ni)
            acc[mi][ni] = __builtin_amdgcn_mfma_f32_16x16x32_bf16(af[mi], wf[ni], acc[mi][ni], 0, 0, 0);
}

// legacy whole-step compute (gemm_levels only)
__device__ __forceinline__ void compute64(const u16* As, const u16* Ws, int wm, int wn,
                                          int l16, int q, f32x4 (&acc)[4][4]) {
#pragma unroll
    for (int kk = 0; kk < 2; ++kk) {
        bf16x8 af[4], wf[4];
        loadfrags(As, Ws, kk, wm, wn, l16, q, af, wf);
        mfma16(af, wf, acc);
    }
}

// ---- 256-thread helpers (gemm_levels) ----
__device__ __forceinline__ void load_a(const float* xb, size_t plane, int tid, uint4 (&rg)[8]) {
    int pxq = tid & 31, cb = tid >> 5;
    const float* aptr = xb + (size_t)(cb * 8) * plane + pxq * 4;
#pragma unroll
    for (int j = 0; j < 8; ++j)
        rg[j] = *(const uint4*)(aptr + (size_t)j * plane);
}
__device__ __forceinline__ void write_a(const uint4 (&rg)[8], u16* lbuf, int tid) {
    int pxq = tid & 31, cb = tid >> 5;
    const float* rf = (const float*)rg;
#pragma unroll
    for (int pi = 0; pi < 4; ++pi) {
        uint4 o;
        o.x = pk2(rf[0 + pi], rf[4 + pi]);
        o.y = pk2(rf[8 + pi], rf[12 + pi]);
        o.z = pk2(rf[16 + pi], rf[20 + pi]);
        o.w = pk2(rf[24 + pi], rf[28 + pi]);
        int r = pxq * 4 + pi;
        *(uint4*)&lbuf[r * 64 + ((cb ^ swz8(r)) << 3)] = o;
    }
}

// ---- 512-thread f1x A-staging ----
__device__ __forceinline__ void loada_f1(const float* xb0, int ktE, int tid, uint4 (&rg)[4]) {
    int pxq = tid & 31, cb = tid >> 5;
    const float* p = xb0 + (size_t)(ktE + cb * 4) * 16384 + pxq * 4;
#pragma unroll
    for (int j = 0; j < 4; ++j)
        rg[j] = *(const uint4*)(p + (size_t)j * 16384);
}
__device__ __forceinline__ void writea_f1(const uint4 (&rg)[4], u16* lbuf, int tid) {
    int pxq = tid & 31, cb = tid >> 5;
    const float* rf = (const float*)rg;
#pragma unroll
    for (int pi = 0; pi < 4; ++pi) {
        uint2 o;
        o.x = pk2(rf[0 + pi], rf[4 + pi]);
        o.y = pk2(rf[8 + pi], rf[12 + pi]);
        int r = pxq * 4 + pi;
        *(uint2*)&lbuf[r * 64 + (((cb >> 1) ^ swz8(r)) << 3) + (cb & 1) * 4] = o;
    }
}

// BN+ReLU on 8 bf16 channels in a uint4
__device__ __forceinline__ uint4 bn8v(uint4 v, f32x4 s0, f32x4 s1, f32x4 h0, f32x4 h1) {
    float sa[8] = {s0[0], s0[1], s0[2], s0[3], s1[0], s1[1], s1[2], s1[3]};
    float ha[8] = {h0[0], h0[1], h0[2], h0[3], h1[0], h1[1], h1[2], h1[3]};
    const uint32_t* w = (const uint32_t*)&v;
    float f[8];
#pragma unroll
    for (int p = 0; p < 4; ++p) {
        f[2 * p]     = fmaxf(__uint_as_float(w[p] << 16) * sa[2 * p] + ha[2 * p], 0.f);
        f[2 * p + 1] = fmaxf(__uint_as_float(w[p] & 0xffff0000u) * sa[2 * p + 1] + ha[2 * p + 1], 0.f);
    }
    uint4 r;
    r.x = pk2(f[0], f[1]); r.y = pk2(f[2], f[3]);
    r.z = pk2(f[4], f[5]); r.w = pk2(f[6], f[7]);
    return r;
}

// ---- 256-thread bn A-staging ----
__device__ __forceinline__ void loada_bn(const char* actb, size_t ldb, int ktB,
                                         uint4 (&rg)[4], int wave, int lr) {
#pragma unroll
    for (int i = 0; i < 4; ++i)
        rg[i] = *(const uint4*)(actb + (size_t)(wave * 32 + i * 8 + lr) * ldb + ktB);
}
__device__ __forceinline__ void writea_bn(const uint4 (&rg)[4], u16* dst,
                                          const float* bns, const float* bnh,
                                          int kb, int wave, int lr, int ch) {
    f32x4 s0 = *(const f32x4*)&bns[kb + ch * 8];
    f32x4 s1 = *(const f32x4*)&bns[kb + ch * 8 + 4];
    f32x4 h0 = *(const f32x4*)&bnh[kb + ch * 8];
    f32x4 h1 = *(const f32x4*)&bnh[kb + ch * 8 + 4];
#pragma unroll
    for (int i = 0; i < 4; ++i) {
        int r = wave * 32 + i * 8 + lr;
        *(uint4*)&dst[r * 64 + ((ch ^ swz8(r)) << 3)] = bn8v(rg[i], s0, s1, h0, h1);
    }
}

// block remap: n-siblings of one m-tile land on the SAME XCD, adjacent in time.
template <int GX>
__device__ __forceinline__ void remap(int& bx, int& by) {
    int f = blockIdx.y * GX + blockIdx.x;
    int r = f & 7, s = f >> 3;
    bx = s % GX;
    by = r + (s / GX) * 8;
}

__device__ __forceinline__ int xcd_swz(int flat, int nwg) {
    int chunk = nwg >> 3;
    return (flat & 7) * chunk + (flat >> 3);
}

// ---------------- merged prep ----------------
__global__ __launch_bounds__(512) void prep(const float* __restrict__ w1,
                                            const float* __restrict__ b1,
                                            const float* __restrict__ w2,
                                            const float* __restrict__ w3,
                                            float* __restrict__ pec,
                                            u16* __restrict__ wb1f,
                                            u16* __restrict__ wb2,
                                            u16* __restrict__ wb3,
                                            float* __restrict__ stats) {
    int blk = blockIdx.x;
    int t = threadIdx.x;
    if (blk < 64) {
        __shared__ float pe[168];
        int dy = blk >> 3, dx = blk & 7;
        if (t < 168) {
            int lv = t / 42, j = t - lv * 42;
            int msk = (1 << lv) - 1;
            float inv = 1.0f / (float)(1 << lv);
            float ry = (float)(2 * (dy & msk) + 1) * inv - 1.0f;
            float rx = (float)(2 * (dx & msk) + 1) * inv - 1.0f;
            float v;
            if (j == 0) v = ry;
            else if (j == 1) v = rx;
            else if (j < 12)  v = sinf(exp2f((float)(j - 2)  * (2.0f/3.0f)) * ry);
            else if (j < 22)  v = sinf(exp2f((float)(j - 12) * (2.0f/3.0f)) * rx);
            else if (j < 32)  v = cosf(exp2f((float)(j - 22) * (2.0f/3.0f)) * ry);
            else              v = cosf(exp2f((float)(j - 32) * (2.0f/3.0f)) * rx);
            pe[t] = v;
        }
        __syncthreads();
        int n = t;
        float acc = b1[n];
#pragma unroll 4
        for (int lv = 0; lv < 4; ++lv)
            for (int j = 0; j < 42; ++j)
                acc += pe[lv * 42 + j] * w1[n * 1192 + lv * 298 + j];
        pec[(size_t)blk * 512 + n] = acc;
    } else if (blk < 320) {
        int i0 = (blk - 64) * 2048 + t;
#pragma unroll
        for (int j = 0; j < 4; ++j) {
            int i = i0 + j * 512;
            int lv = i >> 17;
            int rem = i & 131071;
            int n = rem >> 8, c = rem & 255;
            wb1f[i] = f2b(w1[n * 1192 + lv * 298 + 42 + c]);
        }
    } else if (blk < 384) {
        int i0 = (blk - 320) * 2048 + t;
#pragma unroll
        for (int j = 0; j < 4; ++j) {
            int i = i0 + j * 512;
            wb2[i] = f2b(w2[i]);
        }
    } else if (blk < 416) {
        int i0 = (blk - 384) * 2048 + t;
#pragma unroll
        for (int j = 0; j < 4; ++j) {
            int i = i0 + j * 512;
            wb3[i] = f2b(w3[i]);
        }
    } else {
        for (int i = t; i < 3072; i += 512) stats[i] = 0.f;
    }
}

// ---------------- gemm_bn: 4-wave 128x128, fine 2-phase interleave + setprio ----------------
template <int NT>
__global__ __launch_bounds__(256) void gemm_bn(const u16* __restrict__ W,
                                               const u16* __restrict__ Act,
                                               const float* __restrict__ stats_in,
                                               const float* __restrict__ g,
                                               const float* __restrict__ be,
                                               const float* __restrict__ bias,
                                               u16* __restrict__ Y,
                                               float* __restrict__ stats, int N) {
    constexpr int K = NT * 64;
    __shared__ u16 As[2][8192];
    __shared__ u16 Ws[2][8192];
    __shared__ __align__(16) float bns[512];
    __shared__ __align__(16) float bnh[512];
    int tid = threadIdx.x;
    int wave = tid >> 6, lane = tid & 63;
    int wm = wave >> 1, wn = wave & 1;
    int bx, by;
    remap<2>(bx, by);
    int n0 = bx * 128, m0 = by * 128;
    int q = lane >> 4, l16 = lane & 15;
    f32x4 acc[4][4];
#pragma unroll
    for (int i = 0; i < 4; ++i)
#pragma unroll
        for (int j = 0; j < 4; ++j) acc[i][j] = {0.f, 0.f, 0.f, 0.f};
    int lr = lane >> 3, ch = lane & 7;
    size_t ldb = (size_t)K * 2;
    const char* actb = (const char*)Act + (size_t)m0 * ldb + ch * 16;
    const char* wb = (const char*)W + (size_t)n0 * ldb;

    uint4 rg[2][4];
    stage_tile(wb, ldb, Ws[0], wave, lane);
    loada_bn(actb, ldb, 0, rg[0], wave, lr);
    loada_bn(actb, ldb, 128, rg[1], wave, lr);
    const float inv = 1.0f / (float)MTOT;
    for (int k = tid; k < K; k += 256) {
        float mean = stats_in[k] * inv;
        float var = stats_in[K + k] * inv - mean * mean;
        float s = g[k] * rsqrtf(var + 1e-5f);
        bns[k] = s;
        bnh[k] = be[k] - mean * s;
    }
    __syncthreads();
    writea_bn(rg[0], As[0], bns, bnh, 0, wave, lr, ch);
    asm volatile("s_waitcnt lgkmcnt(0)" ::: "memory");
    __builtin_amdgcn_s_barrier();

#pragma unroll
    for (int t = 0; t < NT; ++t) {
        const u16* Acur = As[t & 1];
        const u16* Wcur = Ws[t & 1];
        bf16x8 af[4], wf[4];
        // ---- phase A (k-slab 0) ----
        if (t + 1 < NT) stage_tile(wb + (size_t)(t + 1) * 128, ldb, Ws[(t + 1) & 1], wave, lane);
        __builtin_amdgcn_sched_barrier(0);
        loadfrags(Acur, Wcur, 0, wm, wn, l16, q, af, wf);
        asm volatile("s_waitcnt lgkmcnt(0)" ::: "memory");
        __builtin_amdgcn_sched_barrier(0);
        __builtin_amdgcn_s_setprio(1);
        mfma16(af, wf, acc);
        __builtin_amdgcn_s_setprio(0);
        // ---- phase B (k-slab 1) ----
        if (t + 2 < NT) loada_bn(actb, ldb, (t + 2) * 128, rg[t & 1], wave, lr);
        if (t + 1 < NT) writea_bn(rg[(t + 1) & 1], As[(t + 1) & 1], bns, bnh, (t + 1) * 64, wave, lr, ch);
        __builtin_amdgcn_sched_barrier(0);
        loadfrags(Acur, Wcur, 1, wm, wn, l16, q, af, wf);
        asm volatile("s_waitcnt lgkmcnt(0)" ::: "memory");
        __builtin_amdgcn_sched_barrier(0);
        __builtin_amdgcn_s_setprio(1);
        mfma16(af, wf, acc);
        __builtin_amdgcn_s_setprio(0);
        if (t + 1 < NT) {
            if (t + 2 < NT) asm volatile("s_waitcnt vmcnt(4) lgkmcnt(0)" ::: "memory");
            else            asm volatile("s_waitcnt vmcnt(0) lgkmcnt(0)" ::: "memory");
            __builtin_amdgcn_s_barrier();
        }
    }

    float bv[4];
#pragma unroll
    for (int ni = 0; ni < 4; ++ni)
        bv[ni] = bias[n0 + wn * 64 + ni * 16 + l16];
    float s1[4] = {0.f, 0.f, 0.f, 0.f}, s2[4] = {0.f, 0.f, 0.f, 0.f};
#pragma unroll
    for (int mi = 0; mi < 4; ++mi) {
#pragma unroll
        for (int r = 0; r < 4; ++r) {
            int m = m0 + wm * 64 + mi * 16 + q * 4 + r;
#pragma unroll
            for (int ni = 0; ni < 4; ++ni) {
                float v = acc[mi][ni][r] + bv[ni];
                Y[(size_t)m * N + (n0 + wn * 64 + ni * 16 + l16)] = f2b(v);
                s1[ni] += v;
                s2[ni] += v * v;
            }
        }
    }
#pragma unroll
    for (int ni = 0; ni < 4; ++ni) {
        float a = s1[ni], bq = s2[ni];
        a += __shfl_xor(a, 16); a += __shfl_xor(a, 32);
        bq += __shfl_xor(bq, 16); bq += __shfl_xor(bq, 32);
        if (q == 0) {
            int n = n0 + wn * 64 + ni * 16 + l16;
            atomicAdd(&stats[n], a);
            atomicAdd(&stats[N + n], bq);
        }
    }
}

// ---------------- merged low-res level GEMMs (unchanged) ----------------
__global__ __launch_bounds__(256) void gemm_levels(const u16* __restrict__ wb1f,
                                                   const float* __restrict__ x2,
                                                   const float* __restrict__ x3,
                                                   const float* __restrict__ x4,
                                                   u16* __restrict__ G1,
                                                   u16* __restrict__ G2,
                                                   u16* __restrict__ G3) {
    __shared__ u16 As[2][8192];
    __shared__ u16 Ws[2][8192];
    int tid = threadIdx.x;
    int wave = tid >> 6, lane = tid & 63;
    int wm = wave >> 1, wn = wave & 1;
    int swz = xcd_swz(blockIdx.y * 4 + blockIdx.x, 672);
    int bx = swz & 3, by = swz >> 2;
    const float* X; u16* G; const u16* W;
    int mt, s2;
    if (by < 128)      { X = x2; G = G1; W = wb1f + 1 * 131072; mt = by;       s2 = 12; }
    else if (by < 160) { X = x3; G = G2; W = wb1f + 2 * 131072; mt = by - 128; s2 = 10; }
    else               { X = x4; G = G3; W = wb1f + 3 * 131072; mt = by - 160; s2 = 8; }
    int n0 = bx * 128, m0 = mt * 128;
    size_t plane = (size_t)1 << s2;
    int b = m0 >> s2;
    int pxbase = m0 & ((1 << s2) - 1);
    const float* xb0 = X + ((size_t)b * 256) * plane + pxbase;
    int q = lane >> 4, l16 = lane & 15;
    f32x4 acc[4][4];
#pragma unroll
    for (int i = 0; i < 4; ++i)
#pragma unroll
        for (int j = 0; j < 4; ++j) acc[i][j] = {0.f, 0.f, 0.f, 0.f};
    const char* wb = (const char*)W + (size_t)n0 * 512;

    uint4 rg[8];
    load_a(xb0, plane, tid, rg);
    stage_tile(wb, 512, Ws[0], wave, lane);
    write_a(rg, As[0], tid);
    __syncthreads();
    int cur = 0;
#pragma unroll
    for (int kt = 64; kt < 256; kt += 64) {
        load_a(xb0 + (size_t)kt * plane, plane, tid, rg);
        stage_tile(wb + kt * 2, 512, Ws[cur ^ 1], wave, lane);
        compute64(As[cur], Ws[cur], wm, wn, l16, q, acc);
        write_a(rg, As[cur ^ 1], tid);
        __syncthreads();
        cur ^= 1;
    }
    compute64(As[cur], Ws[cur], wm, wn, l16, q, acc);

#pragma unroll
    for (int mi = 0; mi < 4; ++mi)
#pragma unroll
        for (int r = 0; r < 4; ++r) {
            int m = m0 + wm * 64 + mi * 16 + q * 4 + r;
#pragma unroll
            for (int ni = 0; ni < 4; ++ni)
                G[(size_t)m * 512 + (n0 + wn * 64 + ni * 16 + l16)] = f2b(acc[mi][ni][r]);
        }
}

// ---------------- 8-wave 128x256 layer-1, fine 2-phase interleave + setprio ----------------
__global__ __launch_bounds__(512) void gemm_f1x(const u16* __restrict__ W,
                                                const float* __restrict__ x1,
                                                const u16* __restrict__ G1,
                                                const u16* __restrict__ G2,
                                                const u16* __restrict__ G3,
                                                const float* __restrict__ pec,
                                                u16* __restrict__ Y,
                                                float* __restrict__ stats) {
    __shared__ u16 As[2][8192];     // [128 px][64 ch] x2
    __shared__ u16 Ws[2][16384];    // [256 n][64 ch] x2
    int tid = threadIdx.x;
    int wave = tid >> 6, lane = tid & 63;
    int wm = wave >> 2, wn = wave & 3;
    int bx, by;
    remap<2>(bx, by);
    int n0 = bx * 256, m0 = by * 128;
    int q = lane >> 4, l16 = lane & 15;
    f32x4 acc[4][4];
#pragma unroll
    for (int i = 0; i < 4; ++i)
#pragma unroll
        for (int j = 0; j < 4; ++j) acc[i][j] = {0.f, 0.f, 0.f, 0.f};
    int b = m0 >> 14;
    int iy = (m0 >> 7) & 127;
    const float* xb0 = x1 + ((size_t)b * 256) * 16384 + (size_t)iy * 128;
    const char* wb = (const char*)W + (size_t)n0 * 512;

    uint4 rg[2][4];
    loada_f1(xb0, 0, tid, rg[0]);             // A(0): 4
    stage_tile(wb, 512, Ws[0], wave, lane);   // W(0): 4
    loada_f1(xb0, 64, tid, rg[1]);            // A(1): 4
    writea_f1(rg[0], As[0], tid);             // retires A(0)
    asm volatile("s_waitcnt vmcnt(4) lgkmcnt(0)" ::: "memory");  // retire W(0); A(1) flies
    __builtin_amdgcn_s_barrier();

#pragma unroll
    for (int t = 0; t < 3; ++t) {
        const u16* Acur = As[t & 1];
        const u16* Wcur = Ws[t & 1];
        bf16x8 af[4], wf[4];
        // ---- phase A (k-slab 0) ----
        stage_tile(wb + (size_t)(t + 1) * 128, 512, Ws[(t + 1) & 1], wave, lane);
        __builtin_amdgcn_sched_barrier(0);
        loadfrags(Acur, Wcur, 0, wm, wn, l16, q, af, wf);
        asm volatile("s_waitcnt lgkmcnt(0)" ::: "memory");
        __builtin_amdgcn_sched_barrier(0);
        __builtin_amdgcn_s_setprio(1);
        mfma16(af, wf, acc);
        __builtin_amdgcn_s_setprio(0);
        // ---- phase B (k-slab 1) ----
        if (t < 2) loada_f1(xb0, (t + 2) * 64, tid, rg[t & 1]);
        writea_f1(rg[(t + 1) & 1], As[(t + 1) & 1], tid);
        __builtin_amdgcn_sched_barrier(0);
        loadfrags(Acur, Wcur, 1, wm, wn, l16, q, af, wf);
        asm volatile("s_waitcnt lgkmcnt(0)" ::: "memory");
        __builtin_amdgcn_sched_barrier(0);
        __builtin_amdgcn_s_setprio(1);
        mfma16(af, wf, acc);
        __builtin_amdgcn_s_setprio(0);
        if (t < 2) asm volatile("s_waitcnt vmcnt(4) lgkmcnt(0)" ::: "memory");
        else       asm volatile("s_waitcnt vmcnt(0) lgkmcnt(0)" ::: "memory");
        __builtin_amdgcn_s_barrier();
    }
    // t = 3: gathers into dead As[0]/Ws[0], then the two compute phases, then drain.
    {
        const char* g1p = (const char*)(G1 + ((size_t)(b * 4096 + (iy >> 1) * 64)) * 512 + n0);
        const char* g2p = (const char*)(G2 + ((size_t)(b * 1024 + (iy >> 2) * 32)) * 512 + n0);
        char* gw = (char*)&Ws[0][0];
        char* ga = (char*)&As[0][0];
#pragma unroll
        for (int it = 0; it < 4; ++it) {
            int u = it * 512 + tid;
            gload16(g1p + (size_t)(u >> 5) * 1024 + (u & 31) * 16, gw + it * 8192 + wave * 1024);
        }
#pragma unroll
        for (int it = 0; it < 2; ++it) {
            int u = it * 512 + tid;
            gload16(g2p + (size_t)(u >> 5) * 1024 + (u & 31) * 16, ga + it * 8192 + wave * 1024);
        }
    }
    {
        bf16x8 af[4], wf[4];
        __builtin_amdgcn_sched_barrier(0);
        loadfrags(As[1], Ws[1], 0, wm, wn, l16, q, af, wf);
        asm volatile("s_waitcnt lgkmcnt(0)" ::: "memory");
        __builtin_amdgcn_sched_barrier(0);
        __builtin_amdgcn_s_setprio(1);
        mfma16(af, wf, acc);
        __builtin_amdgcn_s_setprio(0);
        loadfrags(As[1], Ws[1], 1, wm, wn, l16, q, af, wf);
        asm volatile("s_waitcnt lgkmcnt(0)" ::: "memory");
        __builtin_amdgcn_sched_barrier(0);
        mfma16(af, wf, acc);
    }
    __syncthreads();   // drains gather gloads

    // factored epilogue with line-merged direct stores (round-14 form)
    const u16* g1s = &Ws[0][0];   // [64][256]
    const u16* g2s = &As[0][0];   // [32][256]
    const u16* g3g = G3 + ((size_t)(b * 256 + (iy >> 3) * 16)) * 512 + n0;
    const float* peg = pec + (size_t)((iy & 7) * 8) * 512 + n0;
    int qh = q >> 1, q2 = q * 2, qp = (q & 1) * 4;
    float s1[4] = {0.f, 0.f, 0.f, 0.f}, s2[4] = {0.f, 0.f, 0.f, 0.f};
    float pe[4][4];
#pragma unroll
    for (int ni = 0; ni < 4; ++ni) {
        int nl = wn * 64 + ni * 16 + l16;
#pragma unroll
        for (int r = 0; r < 4; ++r) pe[ni][r] = peg[(size_t)(qp + r) * 512 + nl];
    }
#pragma unroll
    for (int mi = 0; mi < 4; ++mi) {
        float sAv[4], sBv[4];
#pragma unroll
        for (int ni = 0; ni < 4; ++ni) {
            int nl = wn * 64 + ni * 16 + l16;
            float s23 = b2f(g2s[(wm * 16 + mi * 4 + q) * 256 + nl])
                      + b2f(g3g[(size_t)(wm * 8 + mi * 2 + qh) * 512 + nl]);
            sAv[ni] = s23 + b2f(g1s[(wm * 32 + mi * 8 + q2) * 256 + nl]);
            sBv[ni] = s23 + b2f(g1s[(wm * 32 + mi * 8 + q2 + 1) * 256 + nl]);
        }
#pragma unroll
        for (int r = 0; r < 4; ++r) {
            int ix = wm * 64 + mi * 16 + q * 4 + r;
            u16* yrow = &Y[(size_t)(m0 + ix) * 512 + n0 + wn * 64 + l16];
#pragma unroll
            for (int ni = 0; ni < 4; ++ni) {
                float v = acc[mi][ni][r] + (r < 2 ? sAv[ni] : sBv[ni]) + pe[ni][r];
                yrow[ni * 16] = f2b(v);
                s1[ni] += v;
                s2[ni] += v * v;
            }
        }
    }
#pragma unroll
    for (int ni = 0; ni < 4; ++ni) {
        float a = s1[ni], bq = s2[ni];
        a += __shfl_xor(a, 16); a += __shfl_xor(a, 32);
        bq += __shfl_xor(bq, 16); bq += __shfl_xor(bq, 32);
        if (q == 0) {
            int n = n0 + wn * 64 + ni * 16 + l16;
            atomicAdd(&stats[n], a);
            atomicAdd(&stats[512 + n], bq);
        }
    }
}

// ---------------- final: inline BN3 finalize + ReLU + 256 -> 19 conv (grid-stride) ----------------
__global__ __launch_bounds__(256) void gemm4_out(const u16* __restrict__ Y3,
                                                 const float* __restrict__ w4,
                                                 const float* __restrict__ b4,
                                                 const float* __restrict__ stats3,
                                                 const float* __restrict__ g3,
                                                 const float* __restrict__ be3,
                                                 float* __restrict__ out) {
    __shared__ float w4s[19 * 256];
    int t = threadIdx.x;
    for (int i = t; i < 19 * 256; i += 256) w4s[i] = w4[i];
    __syncthreads();
    int mloc = t >> 4, l16 = t & 15;
    const float inv = 1.0f / (float)MTOT;
    float sc[16], sh[16];
#pragma unroll
    for (int j = 0; j < 16; ++j) {
        int c = l16 * 16 + j;
        float mean = stats3[c] * inv;
        float var = stats3[256 + c] * inv - mean * mean;
        float s = g3[c] * rsqrtf(var + 1e-5f);
        sc[j] = s;
        sh[j] = be3[c] - mean * s;
    }
    for (int mt = blockIdx.x; mt < 4096; mt += gridDim.x) {
        int m = mt * 16 + mloc;
        const uint4* yp = (const uint4*)((const char*)Y3 + (size_t)m * 512 + l16 * 32);
        uint4 v0 = yp[0], v1 = yp[1];
        uint32_t uu[8] = {v0.x, v0.y, v0.z, v0.w, v1.x, v1.y, v1.z, v1.w};
        float y[16];
#pragma unroll
        for (int p = 0; p < 8; ++p) {
            y[p * 2]     = __uint_as_float(uu[p] << 16);
            y[p * 2 + 1] = __uint_as_float(uu[p] & 0xffff0000u);
        }
#pragma unroll
        for (int j = 0; j < 16; ++j) y[j] = fmaxf(y[j] * sc[j] + sh[j], 0.f);
        float accv[19];
#pragma unroll
        for (int c = 0; c < 19; ++c) {
            const float* wr = &w4s[c * 256 + l16 * 16];
            float s = 0.f;
#pragma unroll
            for (int j = 0; j < 16; ++j) s += y[j] * wr[j];
            accv[c] = s;
        }
#pragma unroll
        for (int c = 0; c < 19; ++c) {
            float s = accv[c];
            s += __shfl_xor(s, 8, 16);
            s += __shfl_xor(s, 4, 16);
            s += __shfl_xor(s, 2, 16);
            s += __shfl_xor(s, 1, 16);
            accv[c] = s;
        }
        if (l16 == 0) {
            int b = m >> 14, l = m & 16383;
#pragma unroll
            for (int c = 0; c < 19; ++c)
                out[((size_t)b * 19 + c) * 16384 + l] = accv[c] + b4[c];
        }
    }
}

extern "C" void kernel_launch(void* const* d_in, const int* in_sizes, int n_in,
                              void* d_out, int out_size, void* d_ws, size_t ws_size,
                              hipStream_t stream) {
    const float* x1 = (const float*)d_in[0];
    const float* x2 = (const float*)d_in[1];
    const float* x3 = (const float*)d_in[2];
    const float* x4 = (const float*)d_in[3];
    const float* w1 = (const float*)d_in[4];
    const float* b1 = (const float*)d_in[5];
    const float* g1 = (const float*)d_in[6];
    const float* be1 = (const float*)d_in[7];
    const float* w2 = (const float*)d_in[8];
    const float* b2 = (const float*)d_in[9];
    const float* g2 = (const float*)d_in[10];
    const float* be2 = (const float*)d_in[11];
    const float* w3 = (const float*)d_in[12];
    const float* b3 = (const float*)d_in[13];
    const float* g3 = (const float*)d_in[14];
    const float* be3 = (const float*)d_in[15];
    const float* w4 = (const float*)d_in[16];
    const float* b4 = (const float*)d_in[17];

    char* ws = (char*)d_ws;
    u16* Y3  = (u16*)(ws + 0);            // [65536][256]
    u16* Y2  = (u16*)(ws + 33554432);     // [65536][256]
    u16* G1  = (u16*)(ws + 44564480);     // [16384][512]
    u16* G2  = (u16*)(ws + 61341696);     // [4096][512]
    u16* G3  = (u16*)(ws + 65536000);     // [1024][512]
    u16* Y1  = (u16*)(ws + 67108864);     // [65536][512]
    u16* wb1f = (u16*)(ws + 134217728);   // [4][512][256]
    u16* wb2 = (u16*)(ws + 135266304);    // [256][512]
    u16* wb3 = (u16*)(ws + 135528448);    // [256][256]
    float* pec = (float*)(ws + 135659520);// [64][512] f32
    float* stats = (float*)(ws + 135790592);

    prep<<<417, 512, 0, stream>>>(w1, b1, w2, w3, pec, wb1f, wb2, wb3, stats);

    gemm_levels<<<dim3(4, 168), 256, 0, stream>>>(wb1f, x2, x3, x4, G1, G2, G3);

    gemm_f1x<<<dim3(2, 512), 512, 0, stream>>>(wb1f, x1, G1, G2, G3, pec, Y1, stats);

    gemm_bn<8><<<dim3(2, 512), 256, 0, stream>>>(wb2, Y1, stats, g1, be1, b2, Y2,
                                                 stats + 1024, 256);

    gemm_bn<4><<<dim3(2, 512), 256, 0, stream>>>(wb3, Y2, stats + 1024, g2, be2, b3, Y3,
                                                 stats + 2048, 256);

    gemm4_out<<<512, 256, 0, stream>>>(Y3, w4, b4, stats + 2048, g3, be3, (float*)d_out);
}

// Round 16
// 186.933 us; speedup vs baseline: 1.2768x; 1.2768x over previous
//
#include <hip/hip_runtime.h>
#include <hip/hip_bf16.h>
#include <stdint.h>

typedef unsigned short u16;
typedef __bf16 bf16x8 __attribute__((ext_vector_type(8)));
typedef float f32x4 __attribute__((ext_vector_type(4)));

#define MTOT 65536

__device__ __forceinline__ u16 f2b(float f) {
    uint32_t u = __float_as_uint(f);
    u += 0x7fffu + ((u >> 16) & 1u);
    return (u16)(u >> 16);
}
__device__ __forceinline__ float b2f(u16 h) {
    return __uint_as_float(((uint32_t)h) << 16);
}

__device__ __forceinline__ uint32_t pk2(float a, float b) {
    uint32_t r;
    asm("v_cvt_pk_bf16_f32 %0, %1, %2" : "=v"(r) : "v"(a), "v"(b));
    return r;
}

// LDS 16B-chunk swizzle: chunk c of row r lives at slot c ^ swz8(r).
__device__ __forceinline__ int swz8(int r) { return (r ^ (r >> 3)) & 7; }

__device__ __forceinline__ void gload16(const void* g, void* l) {
    __builtin_amdgcn_global_load_lds((const __attribute__((address_space(1))) void*)g,
                                     (__attribute__((address_space(3))) void*)l, 16, 0, 0);
}

// stage a [32*NWAVES x 64] bf16 tile via global_load_lds (4 ops/thread).
__device__ __forceinline__ void stage_tile(const char* gbase, size_t ldb,
                                           u16* lbuf, int wave, int lane) {
    int lr = lane >> 3, lc = lane & 7;
#pragma unroll
    for (int i = 0; i < 4; ++i) {
        int r = wave * 32 + i * 8 + lr;
        int csrc = lc ^ swz8(r);
        gload16(gbase + (size_t)r * ldb + csrc * 16, lbuf + (wave * 32 + i * 8) * 64);
    }
}

// stage a 32x64 bf16 tile (w4) via global_load_lds (1 op/thread, 256 threads)
__device__ __forceinline__ void stage_w4(const char* gbase, u16* lbuf, int wave, int lane) {
    int r = wave * 8 + (lane >> 3), lc = lane & 7;
    int csrc = lc ^ swz8(r);
    gload16(gbase + (size_t)r * 512 + csrc * 16, lbuf + wave * 512);
}

// explicit fragment ds_reads for one 32-wide k-slab
__device__ __forceinline__ void loadfrags(const u16* As, const u16* Ws, int kk,
                                          int wm, int wn, int l16, int q,
                                          bf16x8 (&af)[4], bf16x8 (&wf)[4]) {
    int c0 = kk * 4 + q;
#pragma unroll
    for (int mi = 0; mi < 4; ++mi) {
        int r = wm * 64 + mi * 16 + l16;
        af[mi] = *(const bf16x8*)&As[r * 64 + ((c0 ^ swz8(r)) << 3)];
    }
#pragma unroll
    for (int ni = 0; ni < 4; ++ni) {
        int r = wn * 64 + ni * 16 + l16;
        wf[ni] = *(const bf16x8*)&Ws[r * 64 + ((c0 ^ swz8(r)) << 3)];
    }
}
__device__ __forceinline__ void mfma16(const bf16x8 (&af)[4], const bf16x8 (&wf)[4],
                                       f32x4 (&acc)[4][4]) {
#pragma unroll
    for (int mi = 0; mi < 4; ++mi)
#pragma unroll
        for (int ni = 0; ni < 4; ++ni)
            acc[mi][ni] = __builtin_amdgcn_mfma_f32_16x16x32_bf16(af[mi], wf[ni], acc[mi][ni], 0, 0, 0);
}

// legacy whole-step compute (gemm_levels only)
__device__ __forceinline__ void compute64(const u16* As, const u16* Ws, int wm, int wn,
                                          int l16, int q, f32x4 (&acc)[4][4]) {
#pragma unroll
    for (int kk = 0; kk < 2; ++kk) {
        bf16x8 af[4], wf[4];
        loadfrags(As, Ws, kk, wm, wn, l16, q, af, wf);
        mfma16(af, wf, acc);
    }
}

// ---- 256-thread helpers (gemm_levels) ----
__device__ __forceinline__ void load_a(const float* xb, size_t plane, int tid, uint4 (&rg)[8]) {
    int pxq = tid & 31, cb = tid >> 5;
    const float* aptr = xb + (size_t)(cb * 8) * plane + pxq * 4;
#pragma unroll
    for (int j = 0; j < 8; ++j)
        rg[j] = *(const uint4*)(aptr + (size_t)j * plane);
}
__device__ __forceinline__ void write_a(const uint4 (&rg)[8], u16* lbuf, int tid) {
    int pxq = tid & 31, cb = tid >> 5;
    const float* rf = (const float*)rg;
#pragma unroll
    for (int pi = 0; pi < 4; ++pi) {
        uint4 o;
        o.x = pk2(rf[0 + pi], rf[4 + pi]);
        o.y = pk2(rf[8 + pi], rf[12 + pi]);
        o.z = pk2(rf[16 + pi], rf[20 + pi]);
        o.w = pk2(rf[24 + pi], rf[28 + pi]);
        int r = pxq * 4 + pi;
        *(uint4*)&lbuf[r * 64 + ((cb ^ swz8(r)) << 3)] = o;
    }
}

// ---- 512-thread f1x A-staging ----
__device__ __forceinline__ void loada_f1(const float* xb0, int ktE, int tid, uint4 (&rg)[4]) {
    int pxq = tid & 31, cb = tid >> 5;
    const float* p = xb0 + (size_t)(ktE + cb * 4) * 16384 + pxq * 4;
#pragma unroll
    for (int j = 0; j < 4; ++j)
        rg[j] = *(const uint4*)(p + (size_t)j * 16384);
}
__device__ __forceinline__ void writea_f1(const uint4 (&rg)[4], u16* lbuf, int tid) {
    int pxq = tid & 31, cb = tid >> 5;
    const float* rf = (const float*)rg;
#pragma unroll
    for (int pi = 0; pi < 4; ++pi) {
        uint2 o;
        o.x = pk2(rf[0 + pi], rf[4 + pi]);
        o.y = pk2(rf[8 + pi], rf[12 + pi]);
        int r = pxq * 4 + pi;
        *(uint2*)&lbuf[r * 64 + (((cb >> 1) ^ swz8(r)) << 3) + (cb & 1) * 4] = o;
    }
}

// BN+ReLU on 8 bf16 channels in a uint4
__device__ __forceinline__ uint4 bn8v(uint4 v, f32x4 s0, f32x4 s1, f32x4 h0, f32x4 h1) {
    float sa[8] = {s0[0], s0[1], s0[2], s0[3], s1[0], s1[1], s1[2], s1[3]};
    float ha[8] = {h0[0], h0[1], h0[2], h0[3], h1[0], h1[1], h1[2], h1[3]};
    const uint32_t* w = (const uint32_t*)&v;
    float f[8];
#pragma unroll
    for (int p = 0; p < 4; ++p) {
        f[2 * p]     = fmaxf(__uint_as_float(w[p] << 16) * sa[2 * p] + ha[2 * p], 0.f);
        f[2 * p + 1] = fmaxf(__uint_as_float(w[p] & 0xffff0000u) * sa[2 * p + 1] + ha[2 * p + 1], 0.f);
    }
    uint4 r;
    r.x = pk2(f[0], f[1]); r.y = pk2(f[2], f[3]);
    r.z = pk2(f[4], f[5]); r.w = pk2(f[6], f[7]);
    return r;
}

// ---- 256-thread bn A-staging ----
__device__ __forceinline__ void loada_bn(const char* actb, size_t ldb, int ktB,
                                         uint4 (&rg)[4], int wave, int lr) {
#pragma unroll
    for (int i = 0; i < 4; ++i)
        rg[i] = *(const uint4*)(actb + (size_t)(wave * 32 + i * 8 + lr) * ldb + ktB);
}
__device__ __forceinline__ void writea_bn(const uint4 (&rg)[4], u16* dst,
                                          const float* bns, const float* bnh,
                                          int kb, int wave, int lr, int ch) {
    f32x4 s0 = *(const f32x4*)&bns[kb + ch * 8];
    f32x4 s1 = *(const f32x4*)&bns[kb + ch * 8 + 4];
    f32x4 h0 = *(const f32x4*)&bnh[kb + ch * 8];
    f32x4 h1 = *(const f32x4*)&bnh[kb + ch * 8 + 4];
#pragma unroll
    for (int i = 0; i < 4; ++i) {
        int r = wave * 32 + i * 8 + lr;
        *(uint4*)&dst[r * 64 + ((ch ^ swz8(r)) << 3)] = bn8v(rg[i], s0, s1, h0, h1);
    }
}

// block remap: n-siblings of one m-tile land on the SAME XCD, adjacent in time.
template <int GX>
__device__ __forceinline__ void remap(int& bx, int& by) {
    int f = blockIdx.y * GX + blockIdx.x;
    int r = f & 7, s = f >> 3;
    bx = s % GX;
    by = r + (s / GX) * 8;
}

__device__ __forceinline__ int xcd_swz(int flat, int nwg) {
    int chunk = nwg >> 3;
    return (flat & 7) * chunk + (flat >> 3);
}

// ---------------- merged prep (+ w4 pad/convert) ----------------
__global__ __launch_bounds__(512) void prep(const float* __restrict__ w1,
                                            const float* __restrict__ b1,
                                            const float* __restrict__ w2,
                                            const float* __restrict__ w3,
                                            const float* __restrict__ w4,
                                            float* __restrict__ pec,
                                            u16* __restrict__ wb1f,
                                            u16* __restrict__ wb2,
                                            u16* __restrict__ wb3,
                                            u16* __restrict__ wb4,
                                            float* __restrict__ stats) {
    int blk = blockIdx.x;
    int t = threadIdx.x;
    if (blk < 64) {
        __shared__ float pe[168];
        int dy = blk >> 3, dx = blk & 7;
        if (t < 168) {
            int lv = t / 42, j = t - lv * 42;
            int msk = (1 << lv) - 1;
            float inv = 1.0f / (float)(1 << lv);
            float ry = (float)(2 * (dy & msk) + 1) * inv - 1.0f;
            float rx = (float)(2 * (dx & msk) + 1) * inv - 1.0f;
            float v;
            if (j == 0) v = ry;
            else if (j == 1) v = rx;
            else if (j < 12)  v = sinf(exp2f((float)(j - 2)  * (2.0f/3.0f)) * ry);
            else if (j < 22)  v = sinf(exp2f((float)(j - 12) * (2.0f/3.0f)) * rx);
            else if (j < 32)  v = cosf(exp2f((float)(j - 22) * (2.0f/3.0f)) * ry);
            else              v = cosf(exp2f((float)(j - 32) * (2.0f/3.0f)) * rx);
            pe[t] = v;
        }
        __syncthreads();
        int n = t;
        float acc = b1[n];
#pragma unroll 4
        for (int lv = 0; lv < 4; ++lv)
            for (int j = 0; j < 42; ++j)
                acc += pe[lv * 42 + j] * w1[n * 1192 + lv * 298 + j];
        pec[(size_t)blk * 512 + n] = acc;
    } else if (blk < 320) {
        int i0 = (blk - 64) * 2048 + t;
#pragma unroll
        for (int j = 0; j < 4; ++j) {
            int i = i0 + j * 512;
            int lv = i >> 17;
            int rem = i & 131071;
            int n = rem >> 8, c = rem & 255;
            wb1f[i] = f2b(w1[n * 1192 + lv * 298 + 42 + c]);
        }
    } else if (blk < 384) {
        int i0 = (blk - 320) * 2048 + t;
#pragma unroll
        for (int j = 0; j < 4; ++j) {
            int i = i0 + j * 512;
            wb2[i] = f2b(w2[i]);
        }
    } else if (blk < 416) {
        int i0 = (blk - 384) * 2048 + t;
#pragma unroll
        for (int j = 0; j < 4; ++j) {
            int i = i0 + j * 512;
            wb3[i] = f2b(w3[i]);
        }
    } else if (blk < 420) {
        int i0 = (blk - 416) * 2048 + t;
#pragma unroll
        for (int j = 0; j < 4; ++j) {
            int i = i0 + j * 512;
            int n = i >> 8, c = i & 255;
            wb4[i] = (n < 19) ? f2b(w4[n * 256 + c]) : (u16)0;
        }
    } else {
        for (int i = t; i < 3072; i += 512) stats[i] = 0.f;
    }
}

// ---------------- gemm_bn: 4-wave 128x128, fine 2-phase interleave + setprio ----------------
template <int NT>
__global__ __launch_bounds__(256) void gemm_bn(const u16* __restrict__ W,
                                               const u16* __restrict__ Act,
                                               const float* __restrict__ stats_in,
                                               const float* __restrict__ g,
                                               const float* __restrict__ be,
                                               const float* __restrict__ bias,
                                               u16* __restrict__ Y,
                                               float* __restrict__ stats, int N) {
    constexpr int K = NT * 64;
    __shared__ u16 As[2][8192];
    __shared__ u16 Ws[2][8192];
    __shared__ __align__(16) float bns[512];
    __shared__ __align__(16) float bnh[512];
    int tid = threadIdx.x;
    int wave = tid >> 6, lane = tid & 63;
    int wm = wave >> 1, wn = wave & 1;
    int bx, by;
    remap<2>(bx, by);
    int n0 = bx * 128, m0 = by * 128;
    int q = lane >> 4, l16 = lane & 15;
    f32x4 acc[4][4];
#pragma unroll
    for (int i = 0; i < 4; ++i)
#pragma unroll
        for (int j = 0; j < 4; ++j) acc[i][j] = {0.f, 0.f, 0.f, 0.f};
    int lr = lane >> 3, ch = lane & 7;
    size_t ldb = (size_t)K * 2;
    const char* actb = (const char*)Act + (size_t)m0 * ldb + ch * 16;
    const char* wb = (const char*)W + (size_t)n0 * ldb;

    uint4 rg[2][4];
    stage_tile(wb, ldb, Ws[0], wave, lane);
    loada_bn(actb, ldb, 0, rg[0], wave, lr);
    loada_bn(actb, ldb, 128, rg[1], wave, lr);
    const float inv = 1.0f / (float)MTOT;
    for (int k = tid; k < K; k += 256) {
        float mean = stats_in[k] * inv;
        float var = stats_in[K + k] * inv - mean * mean;
        float s = g[k] * rsqrtf(var + 1e-5f);
        bns[k] = s;
        bnh[k] = be[k] - mean * s;
    }
    __syncthreads();
    writea_bn(rg[0], As[0], bns, bnh, 0, wave, lr, ch);
    asm volatile("s_waitcnt lgkmcnt(0)" ::: "memory");
    __builtin_amdgcn_s_barrier();

#pragma unroll
    for (int t = 0; t < NT; ++t) {
        const u16* Acur = As[t & 1];
        const u16* Wcur = Ws[t & 1];
        bf16x8 af[4], wf[4];
        // ---- phase A (k-slab 0) ----
        if (t + 1 < NT) stage_tile(wb + (size_t)(t + 1) * 128, ldb, Ws[(t + 1) & 1], wave, lane);
        __builtin_amdgcn_sched_barrier(0);
        loadfrags(Acur, Wcur, 0, wm, wn, l16, q, af, wf);
        asm volatile("s_waitcnt lgkmcnt(0)" ::: "memory");
        __builtin_amdgcn_sched_barrier(0);
        __builtin_amdgcn_s_setprio(1);
        mfma16(af, wf, acc);
        __builtin_amdgcn_s_setprio(0);
        // ---- phase B (k-slab 1) ----
        if (t + 2 < NT) loada_bn(actb, ldb, (t + 2) * 128, rg[t & 1], wave, lr);
        if (t + 1 < NT) writea_bn(rg[(t + 1) & 1], As[(t + 1) & 1], bns, bnh, (t + 1) * 64, wave, lr, ch);
        __builtin_amdgcn_sched_barrier(0);
        loadfrags(Acur, Wcur, 1, wm, wn, l16, q, af, wf);
        asm volatile("s_waitcnt lgkmcnt(0)" ::: "memory");
        __builtin_amdgcn_sched_barrier(0);
        __builtin_amdgcn_s_setprio(1);
        mfma16(af, wf, acc);
        __builtin_amdgcn_s_setprio(0);
        if (t + 1 < NT) {
            if (t + 2 < NT) asm volatile("s_waitcnt vmcnt(4) lgkmcnt(0)" ::: "memory");
            else            asm volatile("s_waitcnt vmcnt(0) lgkmcnt(0)" ::: "memory");
            __builtin_amdgcn_s_barrier();
        }
    }

    float bv[4];
#pragma unroll
    for (int ni = 0; ni < 4; ++ni)
        bv[ni] = bias[n0 + wn * 64 + ni * 16 + l16];
    float s1[4] = {0.f, 0.f, 0.f, 0.f}, s2[4] = {0.f, 0.f, 0.f, 0.f};
#pragma unroll
    for (int mi = 0; mi < 4; ++mi) {
#pragma unroll
        for (int r = 0; r < 4; ++r) {
            int m = m0 + wm * 64 + mi * 16 + q * 4 + r;
#pragma unroll
            for (int ni = 0; ni < 4; ++ni) {
                float v = acc[mi][ni][r] + bv[ni];
                Y[(size_t)m * N + (n0 + wn * 64 + ni * 16 + l16)] = f2b(v);
                s1[ni] += v;
                s2[ni] += v * v;
            }
        }
    }
#pragma unroll
    for (int ni = 0; ni < 4; ++ni) {
        float a = s1[ni], bq = s2[ni];
        a += __shfl_xor(a, 16); a += __shfl_xor(a, 32);
        bq += __shfl_xor(bq, 16); bq += __shfl_xor(bq, 32);
        if (q == 0) {
            int n = n0 + wn * 64 + ni * 16 + l16;
            atomicAdd(&stats[n], a);
            atomicAdd(&stats[N + n], bq);
        }
    }
}

// ---------------- merged low-res level GEMMs (unchanged) ----------------
__global__ __launch_bounds__(256) void gemm_levels(const u16* __restrict__ wb1f,
                                                   const float* __restrict__ x2,
                                                   const float* __restrict__ x3,
                                                   const float* __restrict__ x4,
                                                   u16* __restrict__ G1,
                                                   u16* __restrict__ G2,
                                                   u16* __restrict__ G3) {
    __shared__ u16 As[2][8192];
    __shared__ u16 Ws[2][8192];
    int tid = threadIdx.x;
    int wave = tid >> 6, lane = tid & 63;
    int wm = wave >> 1, wn = wave & 1;
    int swz = xcd_swz(blockIdx.y * 4 + blockIdx.x, 672);
    int bx = swz & 3, by = swz >> 2;
    const float* X; u16* G; const u16* W;
    int mt, s2;
    if (by < 128)      { X = x2; G = G1; W = wb1f + 1 * 131072; mt = by;       s2 = 12; }
    else if (by < 160) { X = x3; G = G2; W = wb1f + 2 * 131072; mt = by - 128; s2 = 10; }
    else               { X = x4; G = G3; W = wb1f + 3 * 131072; mt = by - 160; s2 = 8; }
    int n0 = bx * 128, m0 = mt * 128;
    size_t plane = (size_t)1 << s2;
    int b = m0 >> s2;
    int pxbase = m0 & ((1 << s2) - 1);
    const float* xb0 = X + ((size_t)b * 256) * plane + pxbase;
    int q = lane >> 4, l16 = lane & 15;
    f32x4 acc[4][4];
#pragma unroll
    for (int i = 0; i < 4; ++i)
#pragma unroll
        for (int j = 0; j < 4; ++j) acc[i][j] = {0.f, 0.f, 0.f, 0.f};
    const char* wb = (const char*)W + (size_t)n0 * 512;

    uint4 rg[8];
    load_a(xb0, plane, tid, rg);
    stage_tile(wb, 512, Ws[0], wave, lane);
    write_a(rg, As[0], tid);
    __syncthreads();
    int cur = 0;
#pragma unroll
    for (int kt = 64; kt < 256; kt += 64) {
        load_a(xb0 + (size_t)kt * plane, plane, tid, rg);
        stage_tile(wb + kt * 2, 512, Ws[cur ^ 1], wave, lane);
        compute64(As[cur], Ws[cur], wm, wn, l16, q, acc);
        write_a(rg, As[cur ^ 1], tid);
        __syncthreads();
        cur ^= 1;
    }
    compute64(As[cur], Ws[cur], wm, wn, l16, q, acc);

#pragma unroll
    for (int mi = 0; mi < 4; ++mi)
#pragma unroll
        for (int r = 0; r < 4; ++r) {
            int m = m0 + wm * 64 + mi * 16 + q * 4 + r;
#pragma unroll
            for (int ni = 0; ni < 4; ++ni)
                G[(size_t)m * 512 + (n0 + wn * 64 + ni * 16 + l16)] = f2b(acc[mi][ni][r]);
        }
}

// ---------------- 8-wave 128x256 layer-1, fine 2-phase interleave + setprio ----------------
__global__ __launch_bounds__(512) void gemm_f1x(const u16* __restrict__ W,
                                                const float* __restrict__ x1,
                                                const u16* __restrict__ G1,
                                                const u16* __restrict__ G2,
                                                const u16* __restrict__ G3,
                                                const float* __restrict__ pec,
                                                u16* __restrict__ Y,
                                                float* __restrict__ stats) {
    __shared__ u16 As[2][8192];     // [128 px][64 ch] x2
    __shared__ u16 Ws[2][16384];    // [256 n][64 ch] x2
    int tid = threadIdx.x;
    int wave = tid >> 6, lane = tid & 63;
    int wm = wave >> 2, wn = wave & 3;
    int bx, by;
    remap<2>(bx, by);
    int n0 = bx * 256, m0 = by * 128;
    int q = lane >> 4, l16 = lane & 15;
    f32x4 acc[4][4];
#pragma unroll
    for (int i = 0; i < 4; ++i)
#pragma unroll
        for (int j = 0; j < 4; ++j) acc[i][j] = {0.f, 0.f, 0.f, 0.f};
    int b = m0 >> 14;
    int iy = (m0 >> 7) & 127;
    const float* xb0 = x1 + ((size_t)b * 256) * 16384 + (size_t)iy * 128;
    const char* wb = (const char*)W + (size_t)n0 * 512;

    uint4 rg[2][4];
    loada_f1(xb0, 0, tid, rg[0]);             // A(0): 4
    stage_tile(wb, 512, Ws[0], wave, lane);   // W(0): 4
    loada_f1(xb0, 64, tid, rg[1]);            // A(1): 4
    writea_f1(rg[0], As[0], tid);             // retires A(0)
    asm volatile("s_waitcnt vmcnt(4) lgkmcnt(0)" ::: "memory");  // retire W(0); A(1) flies
    __builtin_amdgcn_s_barrier();

#pragma unroll
    for (int t = 0; t < 3; ++t) {
        const u16* Acur = As[t & 1];
        const u16* Wcur = Ws[t & 1];
        bf16x8 af[4], wf[4];
        // ---- phase A (k-slab 0) ----
        stage_tile(wb + (size_t)(t + 1) * 128, 512, Ws[(t + 1) & 1], wave, lane);
        __builtin_amdgcn_sched_barrier(0);
        loadfrags(Acur, Wcur, 0, wm, wn, l16, q, af, wf);
        asm volatile("s_waitcnt lgkmcnt(0)" ::: "memory");
        __builtin_amdgcn_sched_barrier(0);
        __builtin_amdgcn_s_setprio(1);
        mfma16(af, wf, acc);
        __builtin_amdgcn_s_setprio(0);
        // ---- phase B (k-slab 1) ----
        if (t < 2) loada_f1(xb0, (t + 2) * 64, tid, rg[t & 1]);
        writea_f1(rg[(t + 1) & 1], As[(t + 1) & 1], tid);
        __builtin_amdgcn_sched_barrier(0);
        loadfrags(Acur, Wcur, 1, wm, wn, l16, q, af, wf);
        asm volatile("s_waitcnt lgkmcnt(0)" ::: "memory");
        __builtin_amdgcn_sched_barrier(0);
        __builtin_amdgcn_s_setprio(1);
        mfma16(af, wf, acc);
        __builtin_amdgcn_s_setprio(0);
        if (t < 2) asm volatile("s_waitcnt vmcnt(4) lgkmcnt(0)" ::: "memory");
        else       asm volatile("s_waitcnt vmcnt(0) lgkmcnt(0)" ::: "memory");
        __builtin_amdgcn_s_barrier();
    }
    // t = 3: gathers into dead As[0]/Ws[0], then the two compute phases, then drain.
    {
        const char* g1p = (const char*)(G1 + ((size_t)(b * 4096 + (iy >> 1) * 64)) * 512 + n0);
        const char* g2p = (const char*)(G2 + ((size_t)(b * 1024 + (iy >> 2) * 32)) * 512 + n0);
        char* gw = (char*)&Ws[0][0];
        char* ga = (char*)&As[0][0];
#pragma unroll
        for (int it = 0; it < 4; ++it) {
            int u = it * 512 + tid;
            gload16(g1p + (size_t)(u >> 5) * 1024 + (u & 31) * 16, gw + it * 8192 + wave * 1024);
        }
#pragma unroll
        for (int it = 0; it < 2; ++it) {
            int u = it * 512 + tid;
            gload16(g2p + (size_t)(u >> 5) * 1024 + (u & 31) * 16, ga + it * 8192 + wave * 1024);
        }
    }
    {
        bf16x8 af[4], wf[4];
        __builtin_amdgcn_sched_barrier(0);
        loadfrags(As[1], Ws[1], 0, wm, wn, l16, q, af, wf);
        asm volatile("s_waitcnt lgkmcnt(0)" ::: "memory");
        __builtin_amdgcn_sched_barrier(0);
        __builtin_amdgcn_s_setprio(1);
        mfma16(af, wf, acc);
        __builtin_amdgcn_s_setprio(0);
        loadfrags(As[1], Ws[1], 1, wm, wn, l16, q, af, wf);
        asm volatile("s_waitcnt lgkmcnt(0)" ::: "memory");
        __builtin_amdgcn_sched_barrier(0);
        mfma16(af, wf, acc);
    }
    __syncthreads();   // drains gather gloads

    // factored epilogue with line-merged direct stores
    const u16* g1s = &Ws[0][0];   // [64][256]
    const u16* g2s = &As[0][0];   // [32][256]
    const u16* g3g = G3 + ((size_t)(b * 256 + (iy >> 3) * 16)) * 512 + n0;
    const float* peg = pec + (size_t)((iy & 7) * 8) * 512 + n0;
    int qh = q >> 1, q2 = q * 2, qp = (q & 1) * 4;
    float s1[4] = {0.f, 0.f, 0.f, 0.f}, s2[4] = {0.f, 0.f, 0.f, 0.f};
    float pe[4][4];
#pragma unroll
    for (int ni = 0; ni < 4; ++ni) {
        int nl = wn * 64 + ni * 16 + l16;
#pragma unroll
        for (int r = 0; r < 4; ++r) pe[ni][r] = peg[(size_t)(qp + r) * 512 + nl];
    }
#pragma unroll
    for (int mi = 0; mi < 4; ++mi) {
        float sAv[4], sBv[4];
#pragma unroll
        for (int ni = 0; ni < 4; ++ni) {
            int nl = wn * 64 + ni * 16 + l16;
            float s23 = b2f(g2s[(wm * 16 + mi * 4 + q) * 256 + nl])
                      + b2f(g3g[(size_t)(wm * 8 + mi * 2 + qh) * 512 + nl]);
            sAv[ni] = s23 + b2f(g1s[(wm * 32 + mi * 8 + q2) * 256 + nl]);
            sBv[ni] = s23 + b2f(g1s[(wm * 32 + mi * 8 + q2 + 1) * 256 + nl]);
        }
#pragma unroll
        for (int r = 0; r < 4; ++r) {
            int ix = wm * 64 + mi * 16 + q * 4 + r;
            u16* yrow = &Y[(size_t)(m0 + ix) * 512 + n0 + wn * 64 + l16];
#pragma unroll
            for (int ni = 0; ni < 4; ++ni) {
                float v = acc[mi][ni][r] + (r < 2 ? sAv[ni] : sBv[ni]) + pe[ni][r];
                yrow[ni * 16] = f2b(v);
                s1[ni] += v;
                s2[ni] += v * v;
            }
        }
    }
#pragma unroll
    for (int ni = 0; ni < 4; ++ni) {
        float a = s1[ni], bq = s2[ni];
        a += __shfl_xor(a, 16); a += __shfl_xor(a, 32);
        bq += __shfl_xor(bq, 16); bq += __shfl_xor(bq, 32);
        if (q == 0) {
            int n = n0 + wn * 64 + ni * 16 + l16;
            atomicAdd(&stats[n], a);
            atomicAdd(&stats[512 + n], bq);
        }
    }
}

// ---------------- gemm4 via MFMA: Y3[m][256] x w4b[32][256] -> out[b][c][l] f32 ----------------
// 128x32 tile, 4 waves (each owns 32 rows, acc[2][2]), BN3+ReLU fused into A-staging.
__global__ __launch_bounds__(256) void gemm4_mfma(const u16* __restrict__ W,
                                                  const u16* __restrict__ Act,
                                                  const float* __restrict__ stats_in,
                                                  const float* __restrict__ g,
                                                  const float* __restrict__ be,
                                                  const float* __restrict__ b4,
                                                  float* __restrict__ out) {
    __shared__ u16 As[2][8192];     // [128][64]
    __shared__ u16 Ws[2][2048];     // [32][64]
    __shared__ __align__(16) float bns[256];
    __shared__ __align__(16) float bnh[256];
    int tid = threadIdx.x;
    int wave = tid >> 6, lane = tid & 63;
    int q = lane >> 4, l16 = lane & 15;
    int m0 = xcd_swz(blockIdx.x, gridDim.x) * 128;
    f32x4 acc[2][2];
#pragma unroll
    for (int i = 0; i < 2; ++i)
#pragma unroll
        for (int j = 0; j < 2; ++j) acc[i][j] = {0.f, 0.f, 0.f, 0.f};
    int lr = lane >> 3, ch = lane & 7;
    const size_t ldb = 512;
    const char* actb = (const char*)Act + (size_t)m0 * ldb + ch * 16;
    const char* wb = (const char*)W;

    uint4 rg[2][4];
    stage_w4(wb, Ws[0], wave, lane);                 // 1 vmem
    loada_bn(actb, ldb, 0, rg[0], wave, lr);         // 4
    loada_bn(actb, ldb, 128, rg[1], wave, lr);       // 4
    const float inv = 1.0f / (float)MTOT;
    for (int k = tid; k < 256; k += 256) {
        float mean = stats_in[k] * inv;
        float var = stats_in[256 + k] * inv - mean * mean;
        float s = g[k] * rsqrtf(var + 1e-5f);
        bns[k] = s;
        bnh[k] = be[k] - mean * s;
    }
    __syncthreads();   // drains everything
    writea_bn(rg[0], As[0], bns, bnh, 0, wave, lr, ch);
    asm volatile("s_waitcnt lgkmcnt(0)" ::: "memory");
    __builtin_amdgcn_s_barrier();

#pragma unroll
    for (int t = 0; t < 4; ++t) {
        if (t + 1 < 4) stage_w4(wb + (size_t)(t + 1) * 128, Ws[(t + 1) & 1], wave, lane);
        __builtin_amdgcn_sched_barrier(0);
        if (t + 2 < 4) loada_bn(actb, ldb, (t + 2) * 128, rg[t & 1], wave, lr);
        if (t + 1 < 4) writea_bn(rg[(t + 1) & 1], As[(t + 1) & 1], bns, bnh, (t + 1) * 64, wave, lr, ch);
        // compute: 2 k-slabs x acc[2][2]
#pragma unroll
        for (int kk = 0; kk < 2; ++kk) {
            int c0 = kk * 4 + q;
            bf16x8 af[2], wf[2];
#pragma unroll
            for (int mi = 0; mi < 2; ++mi) {
                int r = wave * 32 + mi * 16 + l16;
                af[mi] = *(const bf16x8*)&As[t & 1][r * 64 + ((c0 ^ swz8(r)) << 3)];
            }
#pragma unroll
            for (int ni = 0; ni < 2; ++ni) {
                int r = ni * 16 + l16;
                wf[ni] = *(const bf16x8*)&Ws[t & 1][r * 64 + ((c0 ^ swz8(r)) << 3)];
            }
#pragma unroll
            for (int mi = 0; mi < 2; ++mi)
#pragma unroll
                for (int ni = 0; ni < 2; ++ni)
                    acc[mi][ni] = __builtin_amdgcn_mfma_f32_16x16x32_bf16(af[mi], wf[ni], acc[mi][ni], 0, 0, 0);
        }
        if (t + 1 < 4) {
            if (t + 2 < 4) asm volatile("s_waitcnt vmcnt(4) lgkmcnt(0)" ::: "memory");
            else            asm volatile("s_waitcnt vmcnt(0) lgkmcnt(0)" ::: "memory");
            __builtin_amdgcn_s_barrier();
        }
    }

    // epilogue: write f32 directly in [b][c][l] layout (float4 per (mi,ni), c<19)
    int bb = m0 >> 14;
    int lbase = (m0 & 16383) + wave * 32 + q * 4;
#pragma unroll
    for (int ni = 0; ni < 2; ++ni) {
        int c = ni * 16 + l16;
        if (c < 19) {
            float bvc = b4[c];
            float* op = out + ((size_t)bb * 19 + c) * 16384 + lbase;
#pragma unroll
            for (int mi = 0; mi < 2; ++mi) {
                float4 v;
                v.x = acc[mi][ni][0] + bvc;
                v.y = acc[mi][ni][1] + bvc;
                v.z = acc[mi][ni][2] + bvc;
                v.w = acc[mi][ni][3] + bvc;
                *(float4*)(op + mi * 16) = v;
            }
        }
    }
}

extern "C" void kernel_launch(void* const* d_in, const int* in_sizes, int n_in,
                              void* d_out, int out_size, void* d_ws, size_t ws_size,
                              hipStream_t stream) {
    const float* x1 = (const float*)d_in[0];
    const float* x2 = (const float*)d_in[1];
    const float* x3 = (const float*)d_in[2];
    const float* x4 = (const float*)d_in[3];
    const float* w1 = (const float*)d_in[4];
    const float* b1 = (const float*)d_in[5];
    const float* g1 = (const float*)d_in[6];
    const float* be1 = (const float*)d_in[7];
    const float* w2 = (const float*)d_in[8];
    const float* b2 = (const float*)d_in[9];
    const float* g2 = (const float*)d_in[10];
    const float* be2 = (const float*)d_in[11];
    const float* w3 = (const float*)d_in[12];
    const float* b3 = (const float*)d_in[13];
    const float* g3 = (const float*)d_in[14];
    const float* be3 = (const float*)d_in[15];
    const float* w4 = (const float*)d_in[16];
    const float* b4 = (const float*)d_in[17];

    char* ws = (char*)d_ws;
    u16* Y3  = (u16*)(ws + 0);            // [65536][256]
    u16* Y2  = (u16*)(ws + 33554432);     // [65536][256]
    u16* G1  = (u16*)(ws + 44564480);     // [16384][512]
    u16* G2  = (u16*)(ws + 61341696);     // [4096][512]
    u16* G3  = (u16*)(ws + 65536000);     // [1024][512]
    u16* Y1  = (u16*)(ws + 67108864);     // [65536][512]
    u16* wb1f = (u16*)(ws + 134217728);   // [4][512][256]
    u16* wb2 = (u16*)(ws + 135266304);    // [256][512]
    u16* wb3 = (u16*)(ws + 135528448);    // [256][256]
    float* pec = (float*)(ws + 135659520);// [64][512] f32
    float* stats = (float*)(ws + 135790592);
    u16* wb4 = (u16*)(ws + 135802880);    // [32][256] bf16 (16KB)

    prep<<<421, 512, 0, stream>>>(w1, b1, w2, w3, w4, pec, wb1f, wb2, wb3, wb4, stats);

    gemm_levels<<<dim3(4, 168), 256, 0, stream>>>(wb1f, x2, x3, x4, G1, G2, G3);

    gemm_f1x<<<dim3(2, 512), 512, 0, stream>>>(wb1f, x1, G1, G2, G3, pec, Y1, stats);

    gemm_bn<8><<<dim3(2, 512), 256, 0, stream>>>(wb2, Y1, stats, g1, be1, b2, Y2,
                                                 stats + 1024, 256);

    gemm_bn<4><<<dim3(2, 512), 256, 0, stream>>>(wb3, Y2, stats + 1024, g2, be2, b3, Y3,
                                                 stats + 2048, 256);

    gemm4_mfma<<<512, 256, 0, stream>>>(wb4, Y3, stats + 2048, g3, be3, b4, (float*)d_out);
}